// Round 6
// baseline (52.672 us; speedup 1.0000x reference)
//
#include <hip/hip_runtime.h>
#include <hip/hip_bf16.h>

// SCC: out[b,o,h,w] = sum_{j=0..7} w[o,j] * x[b, (o*4 + j) % 64, h, w]
// B=32, C_IN=C_OUT=64, H=W=128, G=8, STEP=4. All float32.
//
// Round 6: R1/R5 structure (scalar pixel-per-thread, 8192 waves = every
// wave slot, zero redundant traffic) + NON-TEMPORAL on BOTH streams.
// R5 showed nt-stores alone are neutral and the logical-byte rate is
// pinned at ~5.8 TB/s (93% of the cache-interposed copy ceiling) while
// HBM itself demonstrates 7.0 TB/s. Hypothesis: the wall is the
// L2/L3-interposed fabric path; streaming both directions HBM-direct
// (nt loads + nt stores) sidesteps it.

#define CIN   64
#define COUT  64
#define GW    8
#define STEP  4
#define HW    (128 * 128)

__global__ __launch_bounds__(256) void scc_kernel(
    const float* __restrict__ x,
    const float* __restrict__ w,
    float* __restrict__ out,
    int total_pixels)
{
    __shared__ float ws[COUT * GW];
    for (int i = threadIdx.x; i < COUT * GW; i += blockDim.x)
        ws[i] = w[i];
    __syncthreads();

    int p = blockIdx.x * blockDim.x + threadIdx.x;   // pixel id in [0, B*HW)
    if (p >= total_pixels) return;

    int b  = p >> 14;          // p / HW   (HW = 16384 = 2^14)
    int hw = p & (HW - 1);     // p % HW

    const float* xp = x + ((long)b * CIN) * HW + hw;
    float* op       = out + ((long)b * COUT) * HW + hw;

    // Load all 64 channels for this pixel into registers (non-temporal:
    // stream from HBM, don't allocate in L2/L3).
    float xv[CIN];
#pragma unroll
    for (int c = 0; c < CIN; ++c)
        xv[c] = __builtin_nontemporal_load(&xp[(long)c * HW]);

    // Compute all 64 output channels; indices are compile-time constants.
#pragma unroll
    for (int o = 0; o < COUT; ++o) {
        float acc = 0.0f;
#pragma unroll
        for (int j = 0; j < GW; ++j)
            acc = fmaf(ws[o * GW + j], xv[(o * STEP + j) & (CIN - 1)], acc);
        __builtin_nontemporal_store(acc, &op[(long)o * HW]);
    }
}

extern "C" void kernel_launch(void* const* d_in, const int* in_sizes, int n_in,
                              void* d_out, int out_size, void* d_ws, size_t ws_size,
                              hipStream_t stream) {
    const float* x = (const float*)d_in[0];
    const float* w = (const float*)d_in[1];
    float* out     = (float*)d_out;

    const int total_pixels = 32 * HW;   // B * H * W = 524288
    const int block = 256;
    const int grid  = (total_pixels + block - 1) / block;   // 2048

    scc_kernel<<<grid, block, 0, stream>>>(x, w, out, total_pixels);
}

// Round 7
// 45.460 us; speedup vs baseline: 1.1586x; 1.1586x over previous
//
#include <hip/hip_runtime.h>
#include <hip/hip_bf16.h>

// SCC: out[b,o,h,w] = sum_{j=0..7} w[o,j] * x[b, (o*4 + j) % 64, h, w]
// B=32, C_IN=C_OUT=64, H=W=128, G=8, STEP=4. All float32.
//
// FINAL (restores R5, the best-measured config): scalar pixel-per-thread,
// 2048 blocks = 8192 waves (every wave slot on the chip), zero redundant
// traffic (each x byte read exactly once, each out byte written once),
// LDS-staged weights (wave-uniform broadcast reads), non-temporal stores.
//
// Roofline evidence (R1-R6): logical byte rate pins at ~5.8 TB/s across
// all width/occupancy/cache-policy variants; R5 moves 265 MB of actual
// HBM traffic in 46.0 us = 5.76 TB/s = 91% of the measured 6.29 TB/s
// copy ceiling, with compulsory-minimum traffic. Width (f2/f4), more
// waves, redundancy, and read-side L3 bypass all measured neutral or
// negative. Remaining gap vs linear copy is the 64-plane strided access
// pattern inherent to the op.

#define CIN   64
#define COUT  64
#define GW    8
#define STEP  4
#define HW    (128 * 128)

__global__ __launch_bounds__(256) void scc_kernel(
    const float* __restrict__ x,
    const float* __restrict__ w,
    float* __restrict__ out,
    int total_pixels)
{
    __shared__ float ws[COUT * GW];
    for (int i = threadIdx.x; i < COUT * GW; i += blockDim.x)
        ws[i] = w[i];
    __syncthreads();

    int p = blockIdx.x * blockDim.x + threadIdx.x;   // pixel id in [0, B*HW)
    if (p >= total_pixels) return;

    int b  = p >> 14;          // p / HW   (HW = 16384 = 2^14)
    int hw = p & (HW - 1);     // p % HW

    const float* xp = x + ((long)b * CIN) * HW + hw;
    float* op       = out + ((long)b * COUT) * HW + hw;

    // Load all 64 channels for this pixel into registers.
    float xv[CIN];
#pragma unroll
    for (int c = 0; c < CIN; ++c)
        xv[c] = xp[(long)c * HW];

    // Compute all 64 output channels; indices are compile-time constants.
#pragma unroll
    for (int o = 0; o < COUT; ++o) {
        float acc = 0.0f;
#pragma unroll
        for (int j = 0; j < GW; ++j)
            acc = fmaf(ws[o * GW + j], xv[(o * STEP + j) & (CIN - 1)], acc);
        __builtin_nontemporal_store(acc, &op[(long)o * HW]);
    }
}

extern "C" void kernel_launch(void* const* d_in, const int* in_sizes, int n_in,
                              void* d_out, int out_size, void* d_ws, size_t ws_size,
                              hipStream_t stream) {
    const float* x = (const float*)d_in[0];
    const float* w = (const float*)d_in[1];
    float* out     = (float*)d_out;

    const int total_pixels = 32 * HW;   // B * H * W = 524288
    const int block = 256;
    const int grid  = (total_pixels + block - 1) / block;   // 2048

    scc_kernel<<<grid, block, 0, stream>>>(x, w, out, total_pixels);
}